// Round 3
// baseline (137.441 us; speedup 1.0000x reference)
//
#include <hip/hip_runtime.h>
#include <cmath>

// Problem constants (from reference)
#define NUM_B 8
#define NUM_C 4
#define NUM_M 64
#define APT   2        // anchors per thread (small -> 8 blocks/CU, 100% occupancy)
#define BLK   256
constexpr float MAX_POS_D2  = 20.0f * 20.0f;          // dxy_min < 20  <=> d2 < 400
constexpr float BG_POS_D2   = 30.0f * 30.0f;          // dxy_min >= 30 <=> d2 >= 900
constexpr float MAX_ANG     = 15.0f;
constexpr float BG_ANG      = 22.5f;                  // 1.5 * 15
constexpr float ALPHA_C     = 0.95f;
constexpr float EPS_C       = 1e-4f;

// ws layout: ws[b*4 + {0:cls_sum, 1:xy_sum, 2:ang_sum, 3:num_pos}] as double
// __launch_bounds__(256, 8): 8 waves/EU => VGPR cap 64 => 8 blocks/CU resident.
__global__ __launch_bounds__(BLK, 8) void focal_main(
    const float* __restrict__ cls,   // (B, A, 4)
    const float* __restrict__ reg,   // (B, A, 3)
    const float* __restrict__ anc,   // (A, 3)
    const float* __restrict__ ann,   // (B, M, 4)
    double* __restrict__ ws,
    int A)
{
    const int b    = blockIdx.y;
    const int tid  = threadIdx.x;
    const int base = blockIdx.x * (BLK * APT);

    // ---- issue ALL global loads up front so their latency overlaps the
    // min loop (the compiler keeps them in VGPRs; ~45 regs, under the 64 cap).
    float ax[APT], ay[APT], aal[APT];
    float4 cv[APT];
    float rx[APT], ry[APT], ra[APT];
    #pragma unroll
    for (int j = 0; j < APT; ++j) {
        const int a = base + tid + j * BLK;
        const float* ap = anc + 3 * (size_t)a;
        ax[j] = ap[0]; ay[j] = ap[1]; aal[j] = ap[2];        // dwordx3
        cv[j] = *(const float4*)(cls + ((size_t)b * A + a) * NUM_C);
        const float* rp = reg + ((size_t)b * A + a) * 3;
        rx[j] = rp[0]; ry[j] = rp[1]; ra[j] = rp[2];         // dwordx3
    }

    // Stage annotations to LDS once per block.
    // s_xy holds coords masked to 1e18 for invalid annotations -> their d2
    // (~2e36, finite) can never beat any real d2 (<= ~5.3e5), so the
    // branch-free min loop naturally skips them. s_zw holds raw (alpha,label).
    __shared__ float2 s_xy[NUM_M];
    __shared__ float2 s_zw[NUM_M];
    if (tid < NUM_M) {
        const float4 an = ((const float4*)(ann + (size_t)b * NUM_M * 4))[tid];
        const bool valid = (an.w != -1.0f);
        s_xy[tid] = make_float2(valid ? an.x : 1e18f, valid ? an.y : 1e18f);
        s_zw[tid] = make_float2(an.z, an.w);
    }
    __syncthreads();

    float best[APT];
    int besti[APT];
    #pragma unroll
    for (int j = 0; j < APT; ++j) { best[j] = INFINITY; besti[j] = 0; }

    // Branch-free argmin over annotations: 1 ds_read_b64 amortized over
    // APT independent min chains (ILP breaks the cmp->cndmask dep chain).
    #pragma unroll 16
    for (int m = 0; m < NUM_M; ++m) {
        const float2 an = s_xy[m];
        #pragma unroll
        for (int j = 0; j < APT; ++j) {
            const float dx = ax[j] - an.x;
            const float dy = ay[j] - an.y;
            const float d2 = fmaf(dx, dx, dy * dy);
            const bool lt = d2 < best[j];            // strict: first min wins
            best[j]  = lt ? d2 : best[j];
            besti[j] = lt ? m  : besti[j];
        }
    }

    float cls_s = 0.0f, xy_s = 0.0f, ang_s = 0.0f, pos_s = 0.0f;

    #pragma unroll
    for (int j = 0; j < APT; ++j) {
        const int a = base + tid + j * BLK;
        if (a >= A) continue;

        const float2 bxy = s_xy[besti[j]];           // valid winner => raw coords
        const float2 bzw = s_zw[besti[j]];
        const float  dal = fabsf(aal[j] - bzw.x);

        const bool positive   = (best[j] < MAX_POS_D2) && (dal < MAX_ANG);
        const bool background = (best[j] >= BG_POS_D2) || (dal >= BG_ANG);

        int label = (int)bzw.y;                      // trunc, matches astype(int32)
        label = min(max(label, 0), NUM_C - 1);

        // ----- classification (focal) loss -----
        const float cc[4] = {cv[j].x, cv[j].y, cv[j].z, cv[j].w};
        float acc = 0.0f;
        #pragma unroll
        for (int c = 0; c < NUM_C; ++c) {
            const float p = fminf(fmaxf(cc[c], EPS_C), 1.0f - EPS_C);
            const bool is1  = positive && (c == label);  // t == 1
            const float r   = is1 ? (1.0f - p) : p;
            const float af  = is1 ? ALPHA_C : (1.0f - ALPHA_C);
            const float omr = is1 ? p : (1.0f - p);      // 1 - r, >= EPS
            // loss = af * r^2 * (-log(1 - r)); native log (err << 0.179 thr)
            acc += af * r * r * (-__logf(omr));
        }
        cls_s += (positive || background) ? acc : 0.0f;  // t == -1 -> ignored

        // ----- regression loss (positives only) -----
        if (positive) {
            pos_s += 1.0f;
            const float dxr = fabsf((bxy.x - ax[j]) - rx[j]);
            const float dyr = fabsf((bxy.y - ay[j]) - ry[j]);
            const float lx = (dxr <= 1.0f / 9.0f) ? 4.5f * dxr * dxr : dxr - 1.0f / 18.0f;
            const float ly = (dyr <= 1.0f / 9.0f) ? 4.5f * dyr * dyr : dyr - 1.0f / 18.0f;
            xy_s += lx + ly;
            const float dar = fabsf((bzw.x - aal[j]) - ra[j]);
            ang_s += fmaxf((dar - 10.0f) * 0.2f, 0.0f);
        }
    }

    // ----- block reduction: wave64 shuffle -> LDS -> one atomic per block -----
    #pragma unroll
    for (int off = 32; off > 0; off >>= 1) {
        cls_s += __shfl_down(cls_s, off, 64);
        xy_s  += __shfl_down(xy_s,  off, 64);
        ang_s += __shfl_down(ang_s, off, 64);
        pos_s += __shfl_down(pos_s, off, 64);
    }
    __shared__ float s_red[BLK / 64][4];
    const int wave = tid >> 6;
    const int lane = tid & 63;
    if (lane == 0) {
        s_red[wave][0] = cls_s;
        s_red[wave][1] = xy_s;
        s_red[wave][2] = ang_s;
        s_red[wave][3] = pos_s;
    }
    __syncthreads();
    if (tid == 0) {
        float c0 = 0.0f, c1 = 0.0f, c2 = 0.0f, c3 = 0.0f;
        #pragma unroll
        for (int w = 0; w < BLK / 64; ++w) {
            c0 += s_red[w][0];
            c1 += s_red[w][1];
            c2 += s_red[w][2];
            c3 += s_red[w][3];
        }
        atomicAdd(&ws[b * 4 + 0], (double)c0);
        atomicAdd(&ws[b * 4 + 1], (double)c1);
        atomicAdd(&ws[b * 4 + 2], (double)c2);
        atomicAdd(&ws[b * 4 + 3], (double)c3);
    }
}

__global__ void focal_finalize(const double* __restrict__ ws, float* __restrict__ out)
{
    if (threadIdx.x == 0) {
        double sc = 0.0, sx = 0.0, sg = 0.0;
        #pragma unroll
        for (int b = 0; b < NUM_B; ++b) {
            const double denom = fmax(ws[b * 4 + 3], 1.0);
            sc += ws[b * 4 + 0] / denom;
            sx += ws[b * 4 + 1] / (2.0 * denom);
            sg += ws[b * 4 + 2] / denom;
        }
        out[0] = (float)(sc / (double)NUM_B);
        out[1] = (float)(sx / (double)NUM_B);
        out[2] = (float)(sg / (double)NUM_B);
    }
}

extern "C" void kernel_launch(void* const* d_in, const int* in_sizes, int n_in,
                              void* d_out, int out_size, void* d_ws, size_t ws_size,
                              hipStream_t stream)
{
    const float* cls = (const float*)d_in[0];   // (B, A, 4)
    const float* reg = (const float*)d_in[1];   // (B, A, 3)
    const float* anc = (const float*)d_in[2];   // (1, A, 3)
    const float* ann = (const float*)d_in[3];   // (B, M, 4)
    const int A = in_sizes[2] / 3;

    double* ws = (double*)d_ws;
    hipMemsetAsync(d_ws, 0, NUM_B * 4 * sizeof(double), stream);

    dim3 grid((A + BLK * APT - 1) / (BLK * APT), NUM_B);
    focal_main<<<grid, BLK, 0, stream>>>(cls, reg, anc, ann, ws, A);
    focal_finalize<<<1, 64, 0, stream>>>(ws, (float*)d_out);
}

// Round 4
// 100.475 us; speedup vs baseline: 1.3679x; 1.3679x over previous
//
#include <hip/hip_runtime.h>
#include <cmath>

// Problem constants (from reference)
#define NUM_B 8
#define NUM_C 4
#define NUM_M 64
#define APT   8        // anchors per thread: max ILP in min loop, 8x less LDS traffic
#define BLK   256
constexpr float MAX_POS_D2  = 20.0f * 20.0f;          // dxy_min < 20  <=> d2 < 400
constexpr float BG_POS_D2   = 30.0f * 30.0f;          // dxy_min >= 30 <=> d2 >= 900
constexpr float MAX_ANG     = 15.0f;
constexpr float BG_ANG      = 22.5f;                  // 1.5 * 15
constexpr float ALPHA_C     = 0.95f;
constexpr float EPS_C       = 1e-4f;

// ws layout: ws[b*4 + {0:cls_sum, 1:xy_sum, 2:ang_sum, 3:num_pos}] as double
// NOTE: no min-waves-per-EU bound — R3 showed capping VGPRs at 64 makes the
// compiler sink the prefetched loads (VGPR 28) and kills the latency hiding.
__global__ __launch_bounds__(BLK) void focal_main(
    const float* __restrict__ cls,   // (B, A, 4)
    const float* __restrict__ reg,   // (B, A, 3)
    const float* __restrict__ anc,   // (A, 3)
    const float* __restrict__ ann,   // (B, M, 4)
    double* __restrict__ ws,
    int A)
{
    const int b    = blockIdx.y;
    const int tid  = threadIdx.x;
    const int base = blockIdx.x * (BLK * APT);

    // ---- issue ALL global loads up front; their ~500cyc latency drains under
    // the ~3000cyc min loop. Values stay in VGPRs (~130 regs, no cap).
    float ax[APT], ay[APT], aal[APT];
    float4 cv[APT];
    float rx[APT], ry[APT], ra[APT];
    #pragma unroll
    for (int j = 0; j < APT; ++j) {
        const int a  = base + tid + j * BLK;
        const int ac = min(a, A - 1);                         // clamp for safety
        const float* ap = anc + 3 * (size_t)ac;
        ax[j] = ap[0]; ay[j] = ap[1]; aal[j] = ap[2];         // dwordx3
        cv[j] = *(const float4*)(cls + ((size_t)b * A + ac) * NUM_C);
        const float* rp = reg + ((size_t)b * A + ac) * 3;
        rx[j] = rp[0]; ry[j] = rp[1]; ra[j] = rp[2];          // dwordx3
    }

    // Stage annotations to LDS once per block.
    // Min-loop form: argmin d2  <=>  argmax u = ax*anx + ay*any - r/2,
    // where r = anx^2 + any^2 (d2 = q - 2u, q = ax^2+ay^2 per-anchor const).
    // Invalid annotations: rh = 1e36 -> u = -1e36, can never win (finite, no inf).
    __shared__ float4 s_mins[NUM_M];   // (x, y, r/2 masked, pad)
    __shared__ float4 s_ann[NUM_M];    // raw (x, y, alpha, label) for gather
    if (tid < NUM_M) {
        const float4 an = ((const float4*)(ann + (size_t)b * NUM_M * 4))[tid];
        const bool valid = (an.w != -1.0f);
        const float rh = valid ? 0.5f * fmaf(an.x, an.x, an.y * an.y) : 1e36f;
        s_mins[tid] = make_float4(an.x, an.y, rh, 0.0f);
        s_ann[tid]  = an;
    }
    __syncthreads();

    float ub[APT];     // running max of u
    int   ubi[APT];    // its index
    #pragma unroll
    for (int j = 0; j < APT; ++j) { ub[j] = -INFINITY; ubi[j] = 0; }

    // Branch-free argmax: 1 ds_read_b128 + APT x 5 VALU per annotation.
    // Dep chain (fma->fma->cmp->cndmask ~16cyc) << issue (80cyc) -> issue-bound.
    #pragma unroll 16
    for (int m = 0; m < NUM_M; ++m) {
        const float4 an = s_mins[m];
        #pragma unroll
        for (int j = 0; j < APT; ++j) {
            const float t = fmaf(ay[j], an.y, -an.z);
            const float u = fmaf(ax[j], an.x, t);
            const bool gt = u > ub[j];               // strict: first max wins
            ub[j]  = gt ? u : ub[j];
            ubi[j] = gt ? m : ubi[j];
        }
    }

    float cls_s = 0.0f, xy_s = 0.0f, ang_s = 0.0f, pos_s = 0.0f;

    #pragma unroll
    for (int j = 0; j < APT; ++j) {
        const int a = base + tid + j * BLK;
        if (a >= A) continue;

        const float q  = fmaf(ax[j], ax[j], ay[j] * ay[j]);
        const float d2 = fmaf(-2.0f, ub[j], q);      // min squared xy distance
        const float4 ba = s_ann[ubi[j]];             // winner is always valid here
        const float  dal = fabsf(aal[j] - ba.z);

        const bool positive   = (d2 < MAX_POS_D2) && (dal < MAX_ANG);
        const bool background = (d2 >= BG_POS_D2) || (dal >= BG_ANG);

        int label = (int)ba.w;                       // trunc, matches astype(int32)
        label = min(max(label, 0), NUM_C - 1);

        // ----- classification (focal) loss -----
        const float cc[4] = {cv[j].x, cv[j].y, cv[j].z, cv[j].w};
        float acc = 0.0f;
        #pragma unroll
        for (int c = 0; c < NUM_C; ++c) {
            const float p = fminf(fmaxf(cc[c], EPS_C), 1.0f - EPS_C);
            const bool is1  = positive && (c == label);  // t == 1
            const float r   = is1 ? (1.0f - p) : p;
            const float af  = is1 ? ALPHA_C : (1.0f - ALPHA_C);
            const float omr = is1 ? p : (1.0f - p);      // 1 - r, >= EPS
            // loss = af * r^2 * (-log(1 - r)); native log (err << 0.179 thr)
            acc += af * r * r * (-__logf(omr));
        }
        cls_s += (positive || background) ? acc : 0.0f;  // t == -1 -> ignored

        // ----- regression loss (positives only) -----
        if (positive) {
            pos_s += 1.0f;
            const float dxr = fabsf((ba.x - ax[j]) - rx[j]);
            const float dyr = fabsf((ba.y - ay[j]) - ry[j]);
            const float lx = (dxr <= 1.0f / 9.0f) ? 4.5f * dxr * dxr : dxr - 1.0f / 18.0f;
            const float ly = (dyr <= 1.0f / 9.0f) ? 4.5f * dyr * dyr : dyr - 1.0f / 18.0f;
            xy_s += lx + ly;
            const float dar = fabsf((ba.z - aal[j]) - ra[j]);
            ang_s += fmaxf((dar - 10.0f) * 0.2f, 0.0f);
        }
    }

    // ----- block reduction: wave64 shuffle -> LDS -> one atomic per block -----
    #pragma unroll
    for (int off = 32; off > 0; off >>= 1) {
        cls_s += __shfl_down(cls_s, off, 64);
        xy_s  += __shfl_down(xy_s,  off, 64);
        ang_s += __shfl_down(ang_s, off, 64);
        pos_s += __shfl_down(pos_s, off, 64);
    }
    __shared__ float s_red[BLK / 64][4];
    const int wave = tid >> 6;
    const int lane = tid & 63;
    if (lane == 0) {
        s_red[wave][0] = cls_s;
        s_red[wave][1] = xy_s;
        s_red[wave][2] = ang_s;
        s_red[wave][3] = pos_s;
    }
    __syncthreads();
    if (tid == 0) {
        float c0 = 0.0f, c1 = 0.0f, c2 = 0.0f, c3 = 0.0f;
        #pragma unroll
        for (int w = 0; w < BLK / 64; ++w) {
            c0 += s_red[w][0];
            c1 += s_red[w][1];
            c2 += s_red[w][2];
            c3 += s_red[w][3];
        }
        atomicAdd(&ws[b * 4 + 0], (double)c0);
        atomicAdd(&ws[b * 4 + 1], (double)c1);
        atomicAdd(&ws[b * 4 + 2], (double)c2);
        atomicAdd(&ws[b * 4 + 3], (double)c3);
    }
}

__global__ void focal_finalize(const double* __restrict__ ws, float* __restrict__ out)
{
    if (threadIdx.x == 0) {
        double sc = 0.0, sx = 0.0, sg = 0.0;
        #pragma unroll
        for (int b = 0; b < NUM_B; ++b) {
            const double denom = fmax(ws[b * 4 + 3], 1.0);
            sc += ws[b * 4 + 0] / denom;
            sx += ws[b * 4 + 1] / (2.0 * denom);
            sg += ws[b * 4 + 2] / denom;
        }
        out[0] = (float)(sc / (double)NUM_B);
        out[1] = (float)(sx / (double)NUM_B);
        out[2] = (float)(sg / (double)NUM_B);
    }
}

extern "C" void kernel_launch(void* const* d_in, const int* in_sizes, int n_in,
                              void* d_out, int out_size, void* d_ws, size_t ws_size,
                              hipStream_t stream)
{
    const float* cls = (const float*)d_in[0];   // (B, A, 4)
    const float* reg = (const float*)d_in[1];   // (B, A, 3)
    const float* anc = (const float*)d_in[2];   // (1, A, 3)
    const float* ann = (const float*)d_in[3];   // (B, M, 4)
    const int A = in_sizes[2] / 3;

    double* ws = (double*)d_ws;
    hipMemsetAsync(d_ws, 0, NUM_B * 4 * sizeof(double), stream);

    dim3 grid((A + BLK * APT - 1) / (BLK * APT), NUM_B);
    focal_main<<<grid, BLK, 0, stream>>>(cls, reg, anc, ann, ws, A);
    focal_finalize<<<1, 64, 0, stream>>>(ws, (float*)d_out);
}